// Round 8
// baseline (222.728 us; speedup 1.0000x reference)
//
#include <hip/hip_runtime.h>
#include <hip/hip_bf16.h>
#include <math.h>

#define B_SZ 2048
#define K_SZ 100000
#define D_SZ 50
#define BT   64       // batch rows per block (8 waves, 512 thr, j=2). r14/r20 measured finer
                      // decompositions (BT=32, 16-wave/1024thr): both regress (overhead/FLOP,
                      // bank conflicts, barrier convoy). Keep 8 waves x j=2.
#define CK   64       // r15 measured CK=128 image: regression. 64-k chunks; r19 pairs two
                      // chunks into one K=32 ph2 (lower/upper MFMA slots, no shuffles).
#define STR  72        // img Mhi row stride in 2B units; 144 B
#define MTS  78        // precompute Mt scratch stride (odd dword stride -> ~2-way scatter)
#define SHIFT 30.0f    // bf16 P: fp32 exponent range, no subnormal cliff (f16 failed r4)
#define LOG2E 1.4426950408889634f
#define SHIFT_L2 43.280851226668905f   // SHIFT * LOG2E
#define PSTRIDE 52
#define NCH   1563     // ceil(100000/64)
#define IMG_CH 9216    // 2B units per chunk image: 2 * 64 * STR  ([Mhi bf16 | Mt bf16])
#define IMG_BYTES ((size_t)NCH * IMG_CH * 2)
#define PART_BYTES ((size_t)B_SZ * PSTRIDE * sizeof(float))

typedef short short8 __attribute__((ext_vector_type(8)));
typedef short short4v __attribute__((ext_vector_type(4)));
typedef float f32x4 __attribute__((ext_vector_type(4)));

__device__ __forceinline__ unsigned short bf16_rne(float f) {
    union { float f; unsigned int u; } v; v.f = f;
    unsigned int r = (v.u + 0x7fffu + ((v.u >> 16) & 1u)) >> 16;
    return (unsigned short)r;
}
__device__ __forceinline__ float bf16_to_f(unsigned short h) {
    union { unsigned int u; float f; } v; v.u = ((unsigned int)h) << 16;
    return v.f;
}

// ---------------- prologue: M -> per-chunk image [Mhi bf16 | Mt bf16] ----------------
// r7 structure, de-conflicted scatter (MTS=78). NO __threadfence (r11: +120us).
// r21: also zeroes the atomic partial buffer (folds out the hipMemsetAsync dispatch).
__global__ __launch_bounds__(256)
void precompute_m(const float* __restrict__ M, unsigned short* __restrict__ img,
                  float* __restrict__ part) {
    __shared__ __align__(16) unsigned short Mt[64 * MTS];   // transpose scratch (9984 B)
    const int t = threadIdx.x;
    const int c0 = blockIdx.x;
    const int k0 = c0 * 64;
    // zero the [2048][52] partial buffer (stream-ordered before attend's atomics)
    for (int i = c0 * 256 + t; i < B_SZ * PSTRIDE; i += NCH * 256) part[i] = 0.f;
    for (int i = t; i < (64 * MTS) / 2; i += 256) ((unsigned int*)Mt)[i] = 0;
    __syncthreads();
    unsigned int* gh = (unsigned int*)(img + (size_t)c0 * IMG_CH);   // 2304 dwords
    for (int i = t; i < 64 * 36; i += 256) {
        int r = i / 36, cd = i - r * 36, c = cd * 2;
        int kg = k0 + r;
        unsigned int val = 0;
        if (kg < K_SZ && c < D_SZ) {
            float2 v = *(const float2*)&M[(size_t)kg * D_SZ + c];
            val = ((unsigned int)bf16_rne(v.y) << 16) | bf16_rne(v.x);
            Mt[c * MTS + r]       = (unsigned short)(val & 0xffffu);  // one-time transpose
            Mt[(c + 1) * MTS + r] = (unsigned short)(val >> 16);
        }
        gh[i] = val;
    }
    __syncthreads();
    // copy-out: image d-row r, dwords c=0..35 (u16 pairs 2c,2c+1; cols >=64 are zero pad)
    unsigned int* gt = (unsigned int*)(img + (size_t)c0 * IMG_CH + 64 * STR);
    for (int i = t; i < 64 * 36; i += 256) {
        int r = i / 36, c = i - r * 36;
        gt[i] = *(const unsigned int*)&Mt[r * MTS + c * 2];   // dword-aligned (MTS even)
    }
}

// ph1 + exp for one chunk: S = ah . (xh + xl)^T, then pa[j] = packed bf16 exp(S - SHIFT).
// Numeric order identical to r19 (absmax-stable).
__device__ __forceinline__ void ph1exp(const short8 (&ah)[2],
                                       const short8 (&xh)[2][2], const short8 (&xl)[2][2],
                                       float (&lac)[2], unsigned int (&pa)[2][2]) {
    f32x4 S[2] = {};
#pragma unroll
    for (int ki = 0; ki < 2; ++ki) {
#pragma unroll
        for (int j = 0; j < 2; ++j) {
            S[j] = __builtin_amdgcn_mfma_f32_16x16x32_bf16(ah[ki], xh[j][ki], S[j], 0, 0, 0);
            S[j] = __builtin_amdgcn_mfma_f32_16x16x32_bf16(ah[ki], xl[j][ki], S[j], 0, 0, 0);
        }
    }
#pragma unroll
    for (int j = 0; j < 2; ++j) {
        float p0 = __builtin_amdgcn_exp2f(fmaf(S[j][0], LOG2E, -SHIFT_L2));
        float p1 = __builtin_amdgcn_exp2f(fmaf(S[j][1], LOG2E, -SHIFT_L2));
        float p2 = __builtin_amdgcn_exp2f(fmaf(S[j][2], LOG2E, -SHIFT_L2));
        float p3 = __builtin_amdgcn_exp2f(fmaf(S[j][3], LOG2E, -SHIFT_L2));
        lac[j] += (p0 + p1) + (p2 + p3);
        __hip_bfloat162 q01 = __float22bfloat162_rn(make_float2(p0, p1));
        __hip_bfloat162 q23 = __float22bfloat162_rn(make_float2(p2, p3));
        __builtin_memcpy(&pa[j][0], &q01, 4);
        __builtin_memcpy(&pa[j][1], &q23, 4);
    }
}

// ---------------- hot kernel (r21: register-streamed, barrier-free main loop) ----------------
// 8 rounds showed dur pinned ~113-119us across occupancy/barrier/work variants; issue ~20%
// busy -> the lockstep DMA->LDS->s_waitcnt(0)->barrier structure is the residual stall.
// r21 removes it: img is L2-resident (3.6MB/XCD) and intra-block reuse is only 2x (L1
// covers it), so each wave global-loads its ah/bm fragments straight to registers, one
// pair-buffer deep. Prefetch placement: next-pair ah after ph1s (ah dead), next-pair bm
// after ph2 (bm dead) -> compiler's counted vmcnt keeps them in flight under compute.
// NO __syncthreads in the main loop; waves fully self-paced. Compute/accumulation order
// byte-identical to r19 (chunk-paired full-rate K=32 ph2).
// launch_bounds (512,4): NEVER force higher waves/EU — r16 measured forced 32-VGPR alloc
// -> x-frag spill -> 1.9GB scratch FETCH, 577us.
__global__ __launch_bounds__(512, 4)
void attend_fast(const float* __restrict__ x, const unsigned short* __restrict__ img,
                 float* __restrict__ part, int slice) {
    __shared__ float Ured[64 * 66];     // 16.9 KB (epilogue only)
    __shared__ float lsc[4][64];

    const int t = threadIdx.x;
    const int w = t >> 6, lane = t & 63;
    const int quad = lane >> 4, lq = lane & 15;

    const int bid = blockIdx.x;
    const int rr = bid >> 3;
    const int split = (rr >> 5) * 8 + (bid & 7);   // same split -> same XCD (L2 locality)
    const int xtile = rr & 31;
    const int b0 = xtile * BT;
    const int kbeg = split * slice;
    const int kend = min(kbeg + slice, K_SZ);

    const int nt0 = (w & 1) * 2;   // this wave's pair of batch 16-tiles
    const int mblk = w >> 1;       // this wave's memrow 16-tile (= its ph2 k-slice)

    // x fragments: direct global load + hi/lo bf16 split (K-loop invariant, cold path)
    short8 xh[2][2], xl[2][2];
    for (int j = 0; j < 2; ++j) {
        int row = b0 + (nt0 + j) * 16 + lq;
        const float* xr = x + (size_t)row * D_SZ;
        for (int ki = 0; ki < 2; ++ki) {
            int d0 = ki * 32 + quad * 8;
            float v[8];
#pragma unroll
            for (int e = 0; e < 8; ++e) v[e] = 0.f;
            if (d0 + 8 <= D_SZ) {
#pragma unroll
                for (int e = 0; e < 4; ++e) {
                    float2 f2 = *(const float2*)&xr[d0 + 2 * e];
                    v[2 * e] = f2.x; v[2 * e + 1] = f2.y;
                }
            } else if (d0 < D_SZ) {            // d0 == 48
                float2 f2 = *(const float2*)&xr[d0];
                v[0] = f2.x; v[1] = f2.y;
            }
            short8 sh, sl;
#pragma unroll
            for (int e = 0; e < 8; ++e) {
                unsigned short h = bf16_rne(v[e]);
                sh[e] = (short)h;
                sl[e] = (short)bf16_rne(v[e] - bf16_to_f(h));
            }
            xh[j][ki] = sh; xl[j][ki] = sl;
        }
    }

    f32x4 Uacc[2][4] = {};         // [batch tile j][d tile dt], partial over k-slice mblk
    float lac[2] = {0.f, 0.f};

    const int ci0 = kbeg >> 6;
    const int nch = (kend - kbeg + CK - 1) / CK;
    const unsigned short* g0 = img + (size_t)ci0 * IMG_CH;     // split base (linear order)

    // per-lane fragment offsets (u16 units)
    const int aoff0 = (mblk * 16 + lq) * STR + quad * 8;       // ph1 ah base (+ki*32)
    const int boff0 = 64 * STR + lq * STR + mblk * 16 + quad * 4;   // ph2 bm base (+dt*16*STR)

    // pair register buffers
    short8 ahA[2], ahB[2];
    short4v bmA[4], bmB[4];

    // prologue: load pair 0 (chunks 0, min(1,nch-1))
    {
        const unsigned short* gA = g0;
        const unsigned short* gB = g0 + (size_t)(nch > 1 ? 1 : 0) * IMG_CH;
        ahA[0] = *(const short8*)&gA[aoff0];
        ahA[1] = *(const short8*)&gA[aoff0 + 32];
        ahB[0] = *(const short8*)&gB[aoff0];
        ahB[1] = *(const short8*)&gB[aoff0 + 32];
#pragma unroll
        for (int dt = 0; dt < 4; ++dt) {
            bmA[dt] = *(const short4v*)&gA[boff0 + dt * 16 * STR];
            bmB[dt] = *(const short4v*)&gB[boff0 + dt * 16 * STR];
        }
    }

    int n = 0;
    for (; n + 2 <= nch; n += 2) {
        // ph1 + exp for both chunks of this pair (consumes ahA/ahB)
        unsigned int paA[2][2], paB[2][2];
        ph1exp(ahA, xh, xl, lac, paA);
        ph1exp(ahB, xh, xl, lac, paB);

        // prefetch next pair's ah (ah regs dead; clamped -> branchless, no OOB)
        {
            int n2 = (n + 2 < nch) ? n + 2 : nch - 1;
            int n3 = (n + 3 < nch) ? n + 3 : nch - 1;
            const unsigned short* gA2 = g0 + (size_t)n2 * IMG_CH;
            const unsigned short* gB2 = g0 + (size_t)n3 * IMG_CH;
            ahA[0] = *(const short8*)&gA2[aoff0];
            ahA[1] = *(const short8*)&gA2[aoff0 + 32];
            ahB[0] = *(const short8*)&gB2[aoff0];
            ahB[1] = *(const short8*)&gB2[aoff0 + 32];
        }

        // combined ph2: U += [P_A | P_B] . [Mt_A | Mt_B], 8 full-rate K=32 MFMAs
#pragma unroll
        for (int dt = 0; dt < 4; ++dt) {
            union { short8 s8; short4v h[2]; } bm;
            bm.h[0] = bmA[dt]; bm.h[1] = bmB[dt];
#pragma unroll
            for (int j = 0; j < 2; ++j) {
                union { short8 s8; unsigned int u[4]; } pa;
                pa.u[0] = paA[j][0]; pa.u[1] = paA[j][1];
                pa.u[2] = paB[j][0]; pa.u[3] = paB[j][1];
                Uacc[j][dt] = __builtin_amdgcn_mfma_f32_16x16x32_bf16(pa.s8, bm.s8, Uacc[j][dt], 0, 0, 0);
            }
        }

        // prefetch next pair's bm (bm regs dead after ph2)
        {
            int n2 = (n + 2 < nch) ? n + 2 : nch - 1;
            int n3 = (n + 3 < nch) ? n + 3 : nch - 1;
            const unsigned short* gA2 = g0 + (size_t)n2 * IMG_CH;
            const unsigned short* gB2 = g0 + (size_t)n3 * IMG_CH;
#pragma unroll
            for (int dt = 0; dt < 4; ++dt) {
                bmA[dt] = *(const short4v*)&gA2[boff0 + dt * 16 * STR];
                bmB[dt] = *(const short4v*)&gB2[boff0 + dt * 16 * STR];
            }
        }
    }

    if (n < nch) {   // odd tail chunk: in ahA/bmA (clamped prefetch); upper slots x 0
        unsigned int paA[2][2];
        ph1exp(ahA, xh, xl, lac, paA);
#pragma unroll
        for (int dt = 0; dt < 4; ++dt) {
            union { short8 s8; short4v h[2]; } bm;
            bm.h[0] = bmA[dt]; bm.h[1] = bmB[dt];   // upper finite (duplicate), x 0 below
#pragma unroll
            for (int j = 0; j < 2; ++j) {
                union { short8 s8; unsigned int u[4]; } pa;
                pa.u[0] = paA[j][0]; pa.u[1] = paA[j][1];
                pa.u[2] = 0u; pa.u[3] = 0u;
                Uacc[j][dt] = __builtin_amdgcn_mfma_f32_16x16x32_bf16(pa.s8, bm.s8, Uacc[j][dt], 0, 0, 0);
            }
        }
    }

    // l reduction across quads (lane^16, lane^32 share a batch column)
    for (int j = 0; j < 2; ++j) {
        float v = lac[j];
        v += __shfl_xor(v, 16);
        v += __shfl_xor(v, 32);
        if (quad == 0) lsc[mblk][(nt0 + j) * 16 + lq] = v;
    }

    // U reduction across the 4 k-slice waves, in LDS
#pragma unroll
    for (int rnd = 0; rnd < 4; ++rnd) {
        __syncthreads();
        if (mblk == rnd) {
#pragma unroll
            for (int j = 0; j < 2; ++j)
#pragma unroll
                for (int dt = 0; dt < 4; ++dt)
#pragma unroll
                    for (int r4 = 0; r4 < 4; ++r4) {
                        int row = (nt0 + j) * 16 + quad * 4 + r4;
                        int col = dt * 16 + lq;
                        if (rnd == 0) Ured[row * 66 + col] = Uacc[j][dt][r4];
                        else          Ured[row * 66 + col] += Uacc[j][dt][r4];
                    }
        }
    }
    __syncthreads();

    // atomic-accumulate partials into the single [2048][52] buffer (r17; summation order
    // only changes at ulp level vs per-split slots)
    float* pp = part + (size_t)b0 * PSTRIDE;
    for (int i = t; i < BT * D_SZ; i += 512) {
        int row = i / D_SZ, d = i - row * D_SZ;
        atomicAdd(&pp[(size_t)row * PSTRIDE + d], Ured[row * 66 + d]);
    }
    if (t < BT) {
        float Ls = lsc[0][t] + lsc[1][t] + lsc[2][t] + lsc[3][t];
        atomicAdd(&pp[(size_t)t * PSTRIDE + D_SZ], Ls);
    }
}

// ---------------- fallback (round-2 kernel) for small ws ----------------
__global__ __launch_bounds__(512, 4)
void attend_partial_v2(const float* __restrict__ x, const float* __restrict__ M,
                       float* __restrict__ part, int slice) {
    __shared__ __align__(16) unsigned short lds[4 * 64 * STR];
    __shared__ float lsc[4][64];
    unsigned short* bufA  = lds;
    unsigned short* bufB  = lds + 64 * STR;
    unsigned short* Mc_hi = lds + 2 * 64 * STR;
    unsigned short* Mc_lo = lds + 3 * 64 * STR;

    const int t = threadIdx.x;
    const int w = t >> 6, lane = t & 63;
    const int quad = lane >> 4, lq = lane & 15;
    const int b0 = blockIdx.x * 64;
    const int split = blockIdx.y;
    const int kbeg = split * slice;
    const int kend = min(kbeg + slice, K_SZ);

    for (int i = t; i < 4 * 64 * STR; i += 512) lds[i] = 0;
    __syncthreads();
    for (int i = t; i < 64 * 25; i += 512) {
        int r = i / 25, cp = i - r * 25, c = cp * 2;
        float2 v = *(const float2*)&x[(size_t)(b0 + r) * D_SZ + c];
        unsigned short h0 = bf16_rne(v.x), h1 = bf16_rne(v.y);
        unsigned short l0 = bf16_rne(v.x - bf16_to_f(h0));
        unsigned short l1 = bf16_rne(v.y - bf16_to_f(h1));
        *(unsigned int*)&bufA[r * STR + c] = ((unsigned int)h1 << 16) | h0;
        *(unsigned int*)&bufB[r * STR + c] = ((unsigned int)l1 << 16) | l0;
    }
    __syncthreads();

    const int nt0 = (w & 1) * 2;
    const int mblk = w >> 1;
    short8 xh[2][2], xl[2][2];
    for (int j = 0; j < 2; ++j)
        for (int ki = 0; ki < 2; ++ki) {
            int off = ((nt0 + j) * 16 + lq) * STR + ki * 32 + quad * 8;
            xh[j][ki] = *(const short8*)&bufA[off];
            xl[j][ki] = *(const short8*)&bufB[off];
        }

    f32x4 Uacc[2] = {};
    float lac[2] = {0.f, 0.f};

    for (int k0 = kbeg; k0 < kend; k0 += CK) {
        __syncthreads();
        for (int i = t; i < 64 * 25; i += 512) {
            int r = i / 25, cp = i - r * 25, c = cp * 2;
            int kg = k0 + r;
            float2 v = make_float2(0.f, 0.f);
            if (kg < kend) v = *(const float2*)&M[(size_t)kg * D_SZ + c];
            unsigned short h0 = bf16_rne(v.x), h1 = bf16_rne(v.y);
            unsigned short l0 = bf16_rne(v.x - bf16_to_f(h0));
            unsigned short l1 = bf16_rne(v.y - bf16_to_f(h1));
            *(unsigned int*)&Mc_hi[r * STR + c] = ((unsigned int)h1 << 16) | h0;
            *(unsigned int*)&Mc_lo[r * STR + c] = ((unsigned int)l1 << 16) | l0;
            bufB[c * STR + r] = h0;
            bufB[(c + 1) * STR + r] = h1;
        }
        __syncthreads();

        f32x4 S[2] = {};
        for (int ki = 0; ki < 2; ++ki) {
            int aoff = (mblk * 16 + lq) * STR + ki * 32 + quad * 8;
            short8 ah = *(const short8*)&Mc_hi[aoff];
            short8 al = *(const short8*)&Mc_lo[aoff];
            for (int j = 0; j < 2; ++j) {
                S[j] = __builtin_amdgcn_mfma_f32_16x16x32_bf16(ah, xh[j][ki], S[j], 0, 0, 0);
                S[j] = __builtin_amdgcn_mfma_f32_16x16x32_bf16(ah, xl[j][ki], S[j], 0, 0, 0);
                S[j] = __builtin_amdgcn_mfma_f32_16x16x32_bf16(al, xh[j][ki], S[j], 0, 0, 0);
            }
        }
        for (int j = 0; j < 2; ++j) {
            unsigned short pb4[4];
#pragma unroll
            for (int r4 = 0; r4 < 4; ++r4) {
                float p = __expf(S[j][r4] - SHIFT);
                lac[j] += p;
                pb4[r4] = bf16_rne(p);
            }
            int b = (nt0 + j) * 16 + lq;
            int n0 = mblk * 16 + quad * 4;
            *(unsigned int*)&bufA[b * STR + n0]     = ((unsigned int)pb4[1] << 16) | pb4[0];
            *(unsigned int*)&bufA[b * STR + n0 + 2] = ((unsigned int)pb4[3] << 16) | pb4[2];
        }
        __syncthreads();
        for (int ki = 0; ki < 2; ++ki) {
            int poff = (mblk * 16 + lq) * STR + ki * 32 + quad * 8;
            short8 ap = *(const short8*)&bufA[poff];
            for (int j = 0; j < 2; ++j) {
                int doff = ((nt0 + j) * 16 + lq) * STR + ki * 32 + quad * 8;
                short8 bm = *(const short8*)&bufB[doff];
                Uacc[j] = __builtin_amdgcn_mfma_f32_16x16x32_bf16(ap, bm, Uacc[j], 0, 0, 0);
            }
        }
    }

    for (int j = 0; j < 2; ++j) {
        float v = lac[j];
        v += __shfl_xor(v, 16);
        v += __shfl_xor(v, 32);
        if (quad == 0) lsc[mblk][(nt0 + j) * 16 + lq] = v;
    }
    __syncthreads();
    float* pp = part + ((size_t)split * B_SZ + b0) * PSTRIDE;
    for (int j = 0; j < 2; ++j) {
        int d = (nt0 + j) * 16 + lq;
        if (d < D_SZ) {
#pragma unroll
            for (int r4 = 0; r4 < 4; ++r4) {
                int b = mblk * 16 + quad * 4 + r4;
                pp[(size_t)b * PSTRIDE + d] = Uacc[j][r4];
            }
        }
    }
    if (t < 64) {
        float Ls = lsc[0][t] + lsc[1][t] + lsc[2][t] + lsc[3][t];
        pp[(size_t)t * PSTRIDE + D_SZ] = Ls;
    }
}

// combine for the atomic path: part is one pre-summed [2048][52] buffer
__global__ __launch_bounds__(256)
void combine_norm(const float* __restrict__ x, const float* __restrict__ part,
                  float* __restrict__ out) {
    const int b = blockIdx.x * 4 + (threadIdx.x >> 6);
    const int t = threadIdx.x & 63;
    if (t < D_SZ) {
        float L = part[(size_t)b * PSTRIDE + D_SZ];
        float acc = part[(size_t)b * PSTRIDE + t];
        out[(size_t)b * (2 * D_SZ) + t] = x[(size_t)b * D_SZ + t];
        out[(size_t)b * (2 * D_SZ) + D_SZ + t] = acc / L;
    }
}

// combine for the fallback path: per-split partial slots
__global__ __launch_bounds__(256)
void combine(const float* __restrict__ x, const float* __restrict__ part,
             float* __restrict__ out, int nsplit) {
    const int b = blockIdx.x * 4 + (threadIdx.x >> 6);
    const int t = threadIdx.x & 63;
    float L = 0.f;
    for (int s = 0; s < nsplit; ++s)
        L += part[((size_t)s * B_SZ + b) * PSTRIDE + D_SZ];
    if (t < D_SZ) {
        float acc = 0.f;
        for (int s = 0; s < nsplit; ++s)
            acc += part[((size_t)s * B_SZ + b) * PSTRIDE + t];
        out[(size_t)b * (2 * D_SZ) + t] = x[(size_t)b * D_SZ + t];
        out[(size_t)b * (2 * D_SZ) + D_SZ + t] = acc / L;
    }
}

extern "C" void kernel_launch(void* const* d_in, const int* in_sizes, int n_in,
                              void* d_out, int out_size, void* d_ws, size_t ws_size,
                              hipStream_t stream) {
    const float* x = (const float*)d_in[0];
    const float* M = (const float*)d_in[1];
    float* out = (float*)d_out;
    const size_t per_split = (size_t)B_SZ * PSTRIDE * sizeof(float);

    if (ws_size >= IMG_BYTES + PART_BYTES) {
        unsigned short* img = (unsigned short*)d_ws;
        float* part = (float*)((char*)d_ws + IMG_BYTES);
        const int ns = 32;                                   // atomic path: ns not ws-capped
        int slice = (((K_SZ + ns - 1) / ns) + 127) & ~127;   // 3200: 128-aligned
        precompute_m<<<NCH, 256, 0, stream>>>(M, img, part); // also zeroes `part`
        attend_fast<<<32 * ns, 512, 0, stream>>>(x, img, part, slice);
        combine_norm<<<B_SZ / 4, 256, 0, stream>>>(x, part, out);
    } else {
        float* part = (float*)d_ws;
        int ns = (int)(ws_size / per_split);
        if (ns > 32) ns = 32;
        if (ns < 1) ns = 1;
        int slice = (K_SZ + ns - 1) / ns;
        dim3 gridA(B_SZ / 64, ns);
        attend_partial_v2<<<gridA, 512, 0, stream>>>(x, M, part, slice);
        combine<<<B_SZ / 4, 256, 0, stream>>>(x, part, out, ns);
    }
}

// Round 9
// 205.692 us; speedup vs baseline: 1.0828x; 1.0828x over previous
//
#include <hip/hip_runtime.h>
#include <hip/hip_bf16.h>
#include <math.h>

#define B_SZ 2048
#define K_SZ 100000
#define D_SZ 50
#define BT   64       // batch rows per block (8 waves, 512 thr, j=2). r14/r20: finer decomps
                      // regress. r21: register streaming regresses (1-deep, exposed L2 latency).
#define CK   64
#define STR  72        // img row stride in 2B units; 144 B
#define MTS  78        // precompute Mt scratch stride (odd dword stride -> ~2-way scatter)
#define SHIFT 30.0f    // bf16 P: fp32 exponent range, no subnormal cliff (f16 failed r4)
#define LOG2E 1.4426950408889634f
#define SHIFT_L2 43.280851226668905f   // SHIFT * LOG2E
#define PSTRIDE 52
#define NCH   1563     // ceil(100000/64)
#define IMG_CH 9216    // 2B units per chunk image: 2 * 64 * STR  ([Mhi bf16 | Mt bf16])
#define IMG_BYTES ((size_t)NCH * IMG_CH * 2)
#define PART_BYTES ((size_t)B_SZ * PSTRIDE * sizeof(float))
#define WVB 2048       // u16 per wave-slice buffer (4 KB): [Mhi 16x128B swz | Mt 64x32B]

typedef short short8 __attribute__((ext_vector_type(8)));
typedef short short4v __attribute__((ext_vector_type(4)));
typedef float f32x4 __attribute__((ext_vector_type(4)));

#if __has_builtin(__builtin_amdgcn_mfma_f32_16x16x16bf16_1k)
#define HAVE_BF16_K16 1
#else
#define HAVE_BF16_K16 0
#endif

__device__ __forceinline__ unsigned short bf16_rne(float f) {
    union { float f; unsigned int u; } v; v.f = f;
    unsigned int r = (v.u + 0x7fffu + ((v.u >> 16) & 1u)) >> 16;
    return (unsigned short)r;
}
__device__ __forceinline__ float bf16_to_f(unsigned short h) {
    union { unsigned int u; float f; } v; v.u = ((unsigned int)h) << 16;
    return v.f;
}

// async global->LDS, 16B per lane; LDS dest = wave-uniform base + lane*16; global src per-lane
__device__ __forceinline__ void load_lds16(const void* g, void* l) {
    __builtin_amdgcn_global_load_lds(
        (const __attribute__((address_space(1))) unsigned int*)g,
        (__attribute__((address_space(3))) unsigned int*)l, 16, 0, 0);
}

// ---------------- prologue: M -> per-chunk image [Mhi bf16 | Mt bf16] ----------------
// r7 structure, de-conflicted scatter (MTS=78). NO __threadfence (r11: +120us).
// Also zeroes the atomic partial buffer (r21: folds out the hipMemsetAsync dispatch).
__global__ __launch_bounds__(256)
void precompute_m(const float* __restrict__ M, unsigned short* __restrict__ img,
                  float* __restrict__ part) {
    __shared__ __align__(16) unsigned short Mt[64 * MTS];   // transpose scratch (9984 B)
    const int t = threadIdx.x;
    const int c0 = blockIdx.x;
    const int k0 = c0 * 64;
    for (int i = c0 * 256 + t; i < B_SZ * PSTRIDE; i += NCH * 256) part[i] = 0.f;
    for (int i = t; i < (64 * MTS) / 2; i += 256) ((unsigned int*)Mt)[i] = 0;
    __syncthreads();
    unsigned int* gh = (unsigned int*)(img + (size_t)c0 * IMG_CH);   // 2304 dwords
    for (int i = t; i < 64 * 36; i += 256) {
        int r = i / 36, cd = i - r * 36, c = cd * 2;
        int kg = k0 + r;
        unsigned int val = 0;
        if (kg < K_SZ && c < D_SZ) {
            float2 v = *(const float2*)&M[(size_t)kg * D_SZ + c];
            val = ((unsigned int)bf16_rne(v.y) << 16) | bf16_rne(v.x);
            Mt[c * MTS + r]       = (unsigned short)(val & 0xffffu);  // one-time transpose
            Mt[(c + 1) * MTS + r] = (unsigned short)(val >> 16);
        }
        gh[i] = val;
    }
    __syncthreads();
    // copy-out: image d-row r, dwords c=0..35 (u16 pairs 2c,2c+1; cols >=64 are zero pad)
    unsigned int* gt = (unsigned int*)(img + (size_t)c0 * IMG_CH + 64 * STR);
    for (int i = t; i < 64 * 36; i += 256) {
        int r = i / 36, c = i - r * 36;
        gt[i] = *(const unsigned int*)&Mt[r * MTS + c * 2];   // dword-aligned (MTS even)
    }
}

// stage this wave's slice of chunk `cbase` into its private 4KB buffer:
//   Mhi: 16 rows (mblk*16..+16) x 128B, XOR-swizzled SOURCE (slot s of row r fetches
//        global slot s^(r&7)) so the ds_read_b128 at LDS row-stride 128B is conflict-free
//        (rule #21: linear LDS dest + pre-swizzled global src; same XOR on the read).
//   Mt : 64 d-rows x 32B (k-cols mblk*16..+16), linear.
__device__ __forceinline__ void stage_slice(const unsigned short* cbase, int mblk, int lane,
                                            unsigned short* wbuf) {
#pragma unroll
    for (int i = 0; i < 2; ++i) {
        int slot = i * 64 + lane;
        int r = slot >> 3, s = slot & 7;
        const unsigned short* g = cbase + (mblk * 16 + r) * STR + ((s ^ (r & 7)) * 8);
        load_lds16(g, wbuf + i * 512);
    }
#pragma unroll
    for (int i = 0; i < 2; ++i) {
        int slot = i * 64 + lane;
        int rr = slot >> 1, h = slot & 1;
        const unsigned short* g = cbase + 64 * STR + rr * STR + mblk * 16 + h * 8;
        load_lds16(g, wbuf + 1024 + i * 512);
    }
}

// ---------------- hot kernel (r22: per-wave private pipelines, zero barriers) ----------------
// 10 rounds: issue ~30% of wall, DMA BW ~25%, residual ~45% = block-wide lockstep (drain +
// __syncthreads each pair; whole block at slowest-wave pace). r21 proved removing staging
// depth is worse (L2-latency-bound). r22 keeps staged-LDS depth but makes it PER-WAVE:
// each wave stages only its own 4KB chunk-slice (Mhi rows mblk*16..+16, Mt cols
// mblk*16..+16 — waves never share data), double-buffered, counted s_waitcnt vmcnt(4)
// (T3/T4 at wave granularity: chunk n+1 stays in flight while computing n). NO
// __syncthreads in the main loop. nt0-pair waves duplicate staging (L2 reads x1.7 — under
// the per-XCD ceiling). Compute body/numerics = r13 (verified; 1k-op ph2).
// launch_bounds (512,4): NEVER force higher waves/EU (r16: forced 32-VGPR alloc ->
// x-frag spill -> 1.9GB scratch FETCH, 577us).
__global__ __launch_bounds__(512, 4)
void attend_fast(const float* __restrict__ x, const unsigned short* __restrict__ img,
                 float* __restrict__ part, int slice) {
    __shared__ __align__(16) unsigned short stg[8 * 2 * WVB];   // 64KB; reused as Ured
    __shared__ float lsc[4][64];

    const int t = threadIdx.x;
    const int w = t >> 6, lane = t & 63;
    const int quad = lane >> 4, lq = lane & 15;

    const int bid = blockIdx.x;
    const int rr = bid >> 3;
    const int split = (rr >> 5) * 8 + (bid & 7);   // same split -> same XCD (L2 locality)
    const int xtile = rr & 31;
    const int b0 = xtile * BT;
    const int kbeg = split * slice;
    const int kend = min(kbeg + slice, K_SZ);

    const int nt0 = (w & 1) * 2;   // this wave's pair of batch 16-tiles
    const int mblk = w >> 1;       // this wave's memrow 16-tile (= its ph2 k-slice)

    // x fragments: direct global load + hi/lo bf16 split (K-loop invariant, cold path)
    short8 xh[2][2], xl[2][2];
    for (int j = 0; j < 2; ++j) {
        int row = b0 + (nt0 + j) * 16 + lq;
        const float* xr = x + (size_t)row * D_SZ;
        for (int ki = 0; ki < 2; ++ki) {
            int d0 = ki * 32 + quad * 8;
            float v[8];
#pragma unroll
            for (int e = 0; e < 8; ++e) v[e] = 0.f;
            if (d0 + 8 <= D_SZ) {
#pragma unroll
                for (int e = 0; e < 4; ++e) {
                    float2 f2 = *(const float2*)&xr[d0 + 2 * e];
                    v[2 * e] = f2.x; v[2 * e + 1] = f2.y;
                }
            } else if (d0 < D_SZ) {            // d0 == 48
                float2 f2 = *(const float2*)&xr[d0];
                v[0] = f2.x; v[1] = f2.y;
            }
            short8 sh, sl;
#pragma unroll
            for (int e = 0; e < 8; ++e) {
                unsigned short h = bf16_rne(v[e]);
                sh[e] = (short)h;
                sl[e] = (short)bf16_rne(v[e] - bf16_to_f(h));
            }
            xh[j][ki] = sh; xl[j][ki] = sl;
        }
    }

    f32x4 Uacc[2][4] = {};         // [batch tile j][d tile dt], partial over k-slice mblk
    float lac[2] = {0.f, 0.f};

    const int ci0 = kbeg >> 6;
    const int nch = (kend - kbeg + CK - 1) / CK;   // >= 13 for all splits
    const unsigned short* g0 = img + (size_t)ci0 * IMG_CH;

    unsigned short* wb0 = stg + (w * 2 + 0) * WVB;
    unsigned short* wb1 = stg + (w * 2 + 1) * WVB;

    // prologue: stage chunks 0 and 1 (8 DMA outstanding)
    stage_slice(g0, mblk, lane, wb0);
    stage_slice(g0 + IMG_CH, mblk, lane, wb1);

    for (int n = 0; n < nch; ++n) {
        // ensure chunk n's 4 DMA landed; keep chunk n+1's 4 in flight (counted vmcnt)
        __builtin_amdgcn_sched_barrier(0);
        if (n + 1 < nch) asm volatile("s_waitcnt vmcnt(4)" ::: "memory");
        else             asm volatile("s_waitcnt vmcnt(0)" ::: "memory");
        __builtin_amdgcn_sched_barrier(0);

        const unsigned short* wb = (n & 1) ? wb1 : wb0;

        // phase 1: S[m=memrow][n=batch], 2-pass (x-side hi/lo); swizzled ah read
        f32x4 S[2] = {};
#pragma unroll
        for (int ki = 0; ki < 2; ++ki) {
            int sidx = (ki * 4 + quad) ^ (lq & 7);
            short8 ah = *(const short8*)&wb[lq * 64 + sidx * 8];
#pragma unroll
            for (int j = 0; j < 2; ++j) {
                S[j] = __builtin_amdgcn_mfma_f32_16x16x32_bf16(ah, xh[j][ki], S[j], 0, 0, 0);
                S[j] = __builtin_amdgcn_mfma_f32_16x16x32_bf16(ah, xl[j][ki], S[j], 0, 0, 0);
            }
        }

#if HAVE_BF16_K16
        short4v pa[2];
#pragma unroll
        for (int j = 0; j < 2; ++j) {
            float p0 = __builtin_amdgcn_exp2f(fmaf(S[j][0], LOG2E, -SHIFT_L2));
            float p1 = __builtin_amdgcn_exp2f(fmaf(S[j][1], LOG2E, -SHIFT_L2));
            float p2 = __builtin_amdgcn_exp2f(fmaf(S[j][2], LOG2E, -SHIFT_L2));
            float p3 = __builtin_amdgcn_exp2f(fmaf(S[j][3], LOG2E, -SHIFT_L2));
            lac[j] += (p0 + p1) + (p2 + p3);
            __hip_bfloat162 q01 = __float22bfloat162_rn(make_float2(p0, p1));
            __hip_bfloat162 q23 = __float22bfloat162_rn(make_float2(p2, p3));
            union { short4v s; unsigned int u[2]; } pk;
            __builtin_memcpy(&pk.u[0], &q01, 4);
            __builtin_memcpy(&pk.u[1], &q23, 4);
            pa[j] = pk.s;
        }
        // phase 2: U += P . M over k-slice [mblk*16,+16), native K=16; bm from Mt slice
#pragma unroll
        for (int dt = 0; dt < 4; ++dt) {
            short4v bm = *(const short4v*)&wb[1024 + (dt * 16 + lq) * 16 + quad * 4];
#pragma unroll
            for (int j = 0; j < 2; ++j)
                Uacc[j][dt] = __builtin_amdgcn_mfma_f32_16x16x16bf16_1k(pa[j], bm, Uacc[j][dt], 0, 0, 0);
        }
#else
        short8 pa[2];
#pragma unroll
        for (int j = 0; j < 2; ++j) {
            float p0 = __builtin_amdgcn_exp2f(fmaf(S[j][0], LOG2E, -SHIFT_L2));
            float p1 = __builtin_amdgcn_exp2f(fmaf(S[j][1], LOG2E, -SHIFT_L2));
            float p2 = __builtin_amdgcn_exp2f(fmaf(S[j][2], LOG2E, -SHIFT_L2));
            float p3 = __builtin_amdgcn_exp2f(fmaf(S[j][3], LOG2E, -SHIFT_L2));
            lac[j] += (p0 + p1) + (p2 + p3);
            __hip_bfloat162 q01 = __float22bfloat162_rn(make_float2(p0, p1));
            __hip_bfloat162 q23 = __float22bfloat162_rn(make_float2(p2, p3));
            union { short8 s; unsigned int u[4]; } pk;
            __builtin_memcpy(&pk.u[0], &q01, 4);
            __builtin_memcpy(&pk.u[1], &q23, 4);
            pk.u[2] = 0; pk.u[3] = 0;
            pa[j] = pk.s;
        }
#pragma unroll
        for (int dt = 0; dt < 4; ++dt) {
            short4v b4 = *(const short4v*)&wb[1024 + (dt * 16 + lq) * 16 + quad * 4];
            short8 b8;
#pragma unroll
            for (int e = 0; e < 4; ++e) { b8[e] = b4[e]; b8[e + 4] = 0; }
#pragma unroll
            for (int j = 0; j < 2; ++j)
                Uacc[j][dt] = __builtin_amdgcn_mfma_f32_16x16x32_bf16(pa[j], b8, Uacc[j][dt], 0, 0, 0);
        }
#endif

        // stage chunk n+2 into the buffer just consumed (ds_reads retired: the compiler's
        // lgkm waits precede the MFMAs above, which precede this in program order)
        if (n + 2 < nch) {
            __builtin_amdgcn_sched_barrier(0);
            stage_slice(g0 + (size_t)(n + 2) * IMG_CH, mblk, lane, (n & 1) ? wb1 : wb0);
        }
    }

    // l reduction across quads (lane^16, lane^32 share a batch column)
    for (int j = 0; j < 2; ++j) {
        float v = lac[j];
        v += __shfl_xor(v, 16);
        v += __shfl_xor(v, 32);
        if (quad == 0) lsc[mblk][(nt0 + j) * 16 + lq] = v;
    }

    // U reduction across the 4 k-slice waves, in LDS (reuse stg as float [64][66])
    float* Ured = (float*)stg;
#pragma unroll
    for (int rnd = 0; rnd < 4; ++rnd) {
        __syncthreads();
        if (mblk == rnd) {
#pragma unroll
            for (int j = 0; j < 2; ++j)
#pragma unroll
                for (int dt = 0; dt < 4; ++dt)
#pragma unroll
                    for (int r4 = 0; r4 < 4; ++r4) {
                        int row = (nt0 + j) * 16 + quad * 4 + r4;
                        int col = dt * 16 + lq;
                        if (rnd == 0) Ured[row * 66 + col] = Uacc[j][dt][r4];
                        else          Ured[row * 66 + col] += Uacc[j][dt][r4];
                    }
        }
    }
    __syncthreads();

    // atomic-accumulate partials into the single [2048][52] buffer (r17; ulp-level order)
    float* pp = part + (size_t)b0 * PSTRIDE;
    for (int i = t; i < BT * D_SZ; i += 512) {
        int row = i / D_SZ, d = i - row * D_SZ;
        atomicAdd(&pp[(size_t)row * PSTRIDE + d], Ured[row * 66 + d]);
    }
    if (t < BT) {
        float Ls = lsc[0][t] + lsc[1][t] + lsc[2][t] + lsc[3][t];
        atomicAdd(&pp[(size_t)t * PSTRIDE + D_SZ], Ls);
    }
}

// ---------------- fallback (round-2 kernel) for small ws ----------------
__global__ __launch_bounds__(512, 4)
void attend_partial_v2(const float* __restrict__ x, const float* __restrict__ M,
                       float* __restrict__ part, int slice) {
    __shared__ __align__(16) unsigned short lds[4 * 64 * STR];
    __shared__ float lsc[4][64];
    unsigned short* bufA  = lds;
    unsigned short* bufB  = lds + 64 * STR;
    unsigned short* Mc_hi = lds + 2 * 64 * STR;
    unsigned short* Mc_lo = lds + 3 * 64 * STR;

    const int t = threadIdx.x;
    const int w = t >> 6, lane = t & 63;
    const int quad = lane >> 4, lq = lane & 15;
    const int b0 = blockIdx.x * 64;
    const int split = blockIdx.y;
    const int kbeg = split * slice;
    const int kend = min(kbeg + slice, K_SZ);

    for (int i = t; i < 4 * 64 * STR; i += 512) lds[i] = 0;
    __syncthreads();
    for (int i = t; i < 64 * 25; i += 512) {
        int r = i / 25, cp = i - r * 25, c = cp * 2;
        float2 v = *(const float2*)&x[(size_t)(b0 + r) * D_SZ + c];
        unsigned short h0 = bf16_rne(v.x), h1 = bf16_rne(v.y);
        unsigned short l0 = bf16_rne(v.x - bf16_to_f(h0));
        unsigned short l1 = bf16_rne(v.y - bf16_to_f(h1));
        *(unsigned int*)&bufA[r * STR + c] = ((unsigned int)h1 << 16) | h0;
        *(unsigned int*)&bufB[r * STR + c] = ((unsigned int)l1 << 16) | l0;
    }
    __syncthreads();

    const int nt0 = (w & 1) * 2;
    const int mblk = w >> 1;
    short8 xh[2][2], xl[2][2];
    for (int j = 0; j < 2; ++j)
        for (int ki = 0; ki < 2; ++ki) {
            int off = ((nt0 + j) * 16 + lq) * STR + ki * 32 + quad * 8;
            xh[j][ki] = *(const short8*)&bufA[off];
            xl[j][ki] = *(const short8*)&bufB[off];
        }

    f32x4 Uacc[2] = {};
    float lac[2] = {0.f, 0.f};

    for (int k0 = kbeg; k0 < kend; k0 += CK) {
        __syncthreads();
        for (int i = t; i < 64 * 25; i += 512) {
            int r = i / 25, cp = i - r * 25, c = cp * 2;
            int kg = k0 + r;
            float2 v = make_float2(0.f, 0.f);
            if (kg < kend) v = *(const float2*)&M[(size_t)kg * D_SZ + c];
            unsigned short h0 = bf16_rne(v.x), h1 = bf16_rne(v.y);
            unsigned short l0 = bf16_rne(v.x - bf16_to_f(h0));
            unsigned short l1 = bf16_rne(v.y - bf16_to_f(h1));
            *(unsigned int*)&Mc_hi[r * STR + c] = ((unsigned int)h1 << 16) | h0;
            *(unsigned int*)&Mc_lo[r * STR + c] = ((unsigned int)l1 << 16) | l0;
            bufB[c * STR + r] = h0;
            bufB[(c + 1) * STR + r] = h1;
        }
        __syncthreads();

        f32x4 S[2] = {};
        for (int ki = 0; ki < 2; ++ki) {
            int aoff = (mblk * 16 + lq) * STR + ki * 32 + quad * 8;
            short8 ah = *(const short8*)&Mc_hi[aoff];
            short8 al = *(const short8*)&Mc_lo[aoff];
            for (int j = 0; j < 2; ++j) {
                S[j] = __builtin_amdgcn_mfma_f32_16x16x32_bf16(ah, xh[j][ki], S[j], 0, 0, 0);
                S[j] = __builtin_amdgcn_mfma_f32_16x16x32_bf16(ah, xl[j][ki], S[j], 0, 0, 0);
                S[j] = __builtin_amdgcn_mfma_f32_16x16x32_bf16(al, xh[j][ki], S[j], 0, 0, 0);
            }
        }
        for (int j = 0; j < 2; ++j) {
            unsigned short pb4[4];
#pragma unroll
            for (int r4 = 0; r4 < 4; ++r4) {
                float p = __expf(S[j][r4] - SHIFT);
                lac[j] += p;
                pb4[r4] = bf16_rne(p);
            }
            int b = (nt0 + j) * 16 + lq;
            int n0 = mblk * 16 + quad * 4;
            *(unsigned int*)&bufA[b * STR + n0]     = ((unsigned int)pb4[1] << 16) | pb4[0];
            *(unsigned int*)&bufA[b * STR + n0 + 2] = ((unsigned int)pb4[3] << 16) | pb4[2];
        }
        __syncthreads();
        for (int ki = 0; ki < 2; ++ki) {
            int poff = (mblk * 16 + lq) * STR + ki * 32 + quad * 8;
            short8 ap = *(const short8*)&bufA[poff];
            for (int j = 0; j < 2; ++j) {
                int doff = ((nt0 + j) * 16 + lq) * STR + ki * 32 + quad * 8;
                short8 bm = *(const short8*)&bufB[doff];
                Uacc[j] = __builtin_amdgcn_mfma_f32_16x16x32_bf16(ap, bm, Uacc[j], 0, 0, 0);
            }
        }
    }

    for (int j = 0; j < 2; ++j) {
        float v = lac[j];
        v += __shfl_xor(v, 16);
        v += __shfl_xor(v, 32);
        if (quad == 0) lsc[mblk][(nt0 + j) * 16 + lq] = v;
    }
    __syncthreads();
    float* pp = part + ((size_t)split * B_SZ + b0) * PSTRIDE;
    for (int j = 0; j < 2; ++j) {
        int d = (nt0 + j) * 16 + lq;
        if (d < D_SZ) {
#pragma unroll
            for (int r4 = 0; r4 < 4; ++r4) {
                int b = mblk * 16 + quad * 4 + r4;
                pp[(size_t)b * PSTRIDE + d] = Uacc[j][r4];
            }
        }
    }
    if (t < 64) {
        float Ls = lsc[0][t] + lsc[1][t] + lsc[2][t] + lsc[3][t];
        pp[(size_t)t * PSTRIDE + D_SZ] = Ls;
    }
}

// combine for the atomic path: part is one pre-summed [2048][52] buffer
__global__ __launch_bounds__(256)
void combine_norm(const float* __restrict__ x, const float* __restrict__ part,
                  float* __restrict__ out) {
    const int b = blockIdx.x * 4 + (threadIdx.x >> 6);
    const int t = threadIdx.x & 63;
    if (t < D_SZ) {
        float L = part[(size_t)b * PSTRIDE + D_SZ];
        float acc = part[(size_t)b * PSTRIDE + t];
        out[(size_t)b * (2 * D_SZ) + t] = x[(size_t)b * D_SZ + t];
        out[(size_t)b * (2 * D_SZ) + D_SZ + t] = acc / L;
    }
}

// combine for the fallback path: per-split partial slots
__global__ __launch_bounds__(256)
void combine(const float* __restrict__ x, const float* __restrict__ part,
             float* __restrict__ out, int nsplit) {
    const int b = blockIdx.x * 4 + (threadIdx.x >> 6);
    const int t = threadIdx.x & 63;
    float L = 0.f;
    for (int s = 0; s < nsplit; ++s)
        L += part[((size_t)s * B_SZ + b) * PSTRIDE + D_SZ];
    if (t < D_SZ) {
        float acc = 0.f;
        for (int s = 0; s < nsplit; ++s)
            acc += part[((size_t)s * B_SZ + b) * PSTRIDE + t];
        out[(size_t)b * (2 * D_SZ) + t] = x[(size_t)b * D_SZ + t];
        out[(size_t)b * (2 * D_SZ) + D_SZ + t] = acc / L;
    }
}

extern "C" void kernel_launch(void* const* d_in, const int* in_sizes, int n_in,
                              void* d_out, int out_size, void* d_ws, size_t ws_size,
                              hipStream_t stream) {
    const float* x = (const float*)d_in[0];
    const float* M = (const float*)d_in[1];
    float* out = (float*)d_out;
    const size_t per_split = (size_t)B_SZ * PSTRIDE * sizeof(float);

    if (ws_size >= IMG_BYTES + PART_BYTES) {
        unsigned short* img = (unsigned short*)d_ws;
        float* part = (float*)((char*)d_ws + IMG_BYTES);
        const int ns = 32;                                   // atomic path: ns not ws-capped
        int slice = (((K_SZ + ns - 1) / ns) + 127) & ~127;   // 3200: 128-aligned
        precompute_m<<<NCH, 256, 0, stream>>>(M, img, part); // also zeroes `part`
        attend_fast<<<32 * ns, 512, 0, stream>>>(x, img, part, slice);
        combine_norm<<<B_SZ / 4, 256, 0, stream>>>(x, part, out);
    } else {
        float* part = (float*)d_ws;
        int ns = (int)(ws_size / per_split);
        if (ns > 32) ns = 32;
        if (ns < 1) ns = 1;
        int slice = (K_SZ + ns - 1) / ns;
        dim3 gridA(B_SZ / 64, ns);
        attend_partial_v2<<<gridA, 512, 0, stream>>>(x, M, part, slice);
        combine<<<B_SZ / 4, 256, 0, stream>>>(x, part, out, ns);
    }
}